// Round 2
// baseline (134.358 us; speedup 1.0000x reference)
//
#include <hip/hip_runtime.h>

// LSSM: x_t = x_{t-1} A^T + u_t B^T ; y_t = x_t C^T + u_t D^T ; x_0 = 0
// B=16, SEQ=8192, all dims 128.
//
// R2 structure: chunked parallel scan, 256 chunks of 32 steps, 2-step-unrolled
// phases (16 barriers/chunk) with fused output matrices:
//   x_{t+2} = x_t (A^2)^T + u_{t+1} (AB)^T + u_{t+2} B^T
//   y_{t+1} = x_t (CA)^T  + u_{t+1} (CB+D)^T
//   y_{t+2} = x_t (CA^2)^T+ u_{t+1} (CAB)^T + u_{t+2} (CB+D)^T
// x-path matrices use full hi/lo bf16 split (3 MFMA per product); y-path
// matrices are hi-only (error ~1e-2, no recurrence amplification).
// State crosses waves through XOR-swizzled LDS (byte ^= (row&7)<<4).

#define SEQ 8192
#define BS  16
#define DD  128
#define CL  32           // chunk length
#define PH  16           // phases per chunk (2 steps each)
#define NC  256          // SEQ / CL
#define GRP 16           // chunks per group
#define NG  16           // NC / GRP

typedef __bf16 bf16t;
typedef __bf16 bf16x8 __attribute__((ext_vector_type(8)));
typedef __bf16 bf16x4 __attribute__((ext_vector_type(4)));
typedef float  f32x4  __attribute__((ext_vector_type(4)));

#define MFMA(a,b,c) __builtin_amdgcn_mfma_f32_16x16x32_bf16(a,b,c,0,0,0)

__device__ __forceinline__ int swz(int b, int j) { return j ^ ((b & 7) << 3); }

struct Frag  { bf16x8 h[4]; bf16x8 l[4]; };
struct FragH { bf16x8 h[4]; };

// B-operand frags of M where M[k][n] = src[n][k]  (src row-major [128][128])
__device__ __forceinline__ void load_frag_T(const float* __restrict__ src, int lane, int w, Frag& f) {
    int n  = (w << 4) + (lane & 15);
    int kb = ((lane >> 4) & 3) << 3;
#pragma unroll
    for (int q = 0; q < 4; q++) {
        const float* p = src + n * DD + (q << 5) + kb;
#pragma unroll
        for (int e = 0; e < 8; e++) {
            float v = p[e];
            bf16t hh = (bf16t)v;
            f.h[q][e] = hh;
            f.l[q][e] = (bf16t)(v - (float)hh);
        }
    }
}

__device__ __forceinline__ void load_frag_T_h(const float* __restrict__ src, int lane, int w, FragH& f) {
    int n  = (w << 4) + (lane & 15);
    int kb = ((lane >> 4) & 3) << 3;
#pragma unroll
    for (int q = 0; q < 4; q++) {
        const float* p = src + n * DD + (q << 5) + kb;
#pragma unroll
        for (int e = 0; e < 8; e++) f.h[q][e] = (bf16t)p[e];
    }
}

// B-operand frags of M where M[k][n] = src[k][n]  (no transpose)
__device__ __forceinline__ void load_frag_N(const float* __restrict__ src, int lane, int w, Frag& f) {
    int n  = (w << 4) + (lane & 15);
    int kb = ((lane >> 4) & 3) << 3;
#pragma unroll
    for (int q = 0; q < 4; q++) {
#pragma unroll
        for (int e = 0; e < 8; e++) {
            float v = src[((q << 5) + kb + e) * DD + n];
            bf16t hh = (bf16t)v;
            f.h[q][e] = hh;
            f.l[q][e] = (bf16t)(v - (float)hh);
        }
    }
}

// A-operand frag from swizzled LDS state [16][128] bf16: lane&15 -> row b
__device__ __forceinline__ bf16x8 afrag(const bf16t* __restrict__ X, int lane, int q) {
    int b  = lane & 15;
    int j0 = (q << 5) + (((lane >> 4) & 3) << 3);
    return *(const bf16x8*)(X + b * DD + swz(b, j0));
}

// D-frag (f32x4) -> hi/lo bf16 swizzled LDS.  D layout: col=lane&15, row=(lane>>4)*4+r
__device__ __forceinline__ void put_state(bf16t* __restrict__ H, bf16t* __restrict__ L,
                                          int lane, int w, f32x4 acc) {
    int n = (w << 4) + (lane & 15);
#pragma unroll
    for (int r = 0; r < 4; r++) {
        int b = (((lane >> 4) & 3) << 2) + r;
        float v = acc[r];
        bf16t hh = (bf16t)v;
        H[b * DD + swz(b, n)] = hh;
        L[b * DD + swz(b, n)] = (bf16t)(v - (float)hh);
    }
}

// cooperative: 16x128 fp32 block (row stride rs) -> hi/lo swizzled LDS (512 thr)
__device__ __forceinline__ void stage_rows(const float* __restrict__ src, long rs,
                                           bf16t* __restrict__ H, bf16t* __restrict__ L, int tid) {
    int b  = tid >> 5;
    int j0 = (tid & 31) << 2;
    float4 v = *(const float4*)(src + (long)b * rs + j0);
    float vv[4] = { v.x, v.y, v.z, v.w };
    bf16x4 h, l;
#pragma unroll
    for (int e = 0; e < 4; e++) {
        bf16t hh = (bf16t)vv[e];
        h[e] = hh;
        l[e] = (bf16t)(vv[e] - (float)hh);
    }
    *(bf16x4*)(H + b * DD + swz(b, j0)) = h;
    *(bf16x4*)(L + b * DD + swz(b, j0)) = l;
}

// per-thread: float4 -> hi/lo bf16x4 into swizzled LDS at (b_, j0_)
__device__ __forceinline__ void write_u(bf16t* __restrict__ H, bf16t* __restrict__ L,
                                        int b_, int j0_, float4 v) {
    float vv[4] = { v.x, v.y, v.z, v.w };
    bf16x4 h, l;
#pragma unroll
    for (int e = 0; e < 4; e++) {
        bf16t hh = (bf16t)vv[e];
        h[e] = hh;
        l[e] = (bf16t)(vv[e] - (float)hh);
    }
    *(bf16x4*)(H + b_ * DD + swz(b_, j0_)) = h;
    *(bf16x4*)(L + b_ * DD + swz(b_, j0_)) = l;
}

__device__ __forceinline__ f32x4 load_accfrag(const float* __restrict__ src, int lane, int w) {
    int n = (w << 4) + (lane & 15);
    f32x4 a;
#pragma unroll
    for (int r = 0; r < 4; r++) {
        int b = (((lane >> 4) & 3) << 2) + r;
        a[r] = src[b * DD + n];
    }
    return a;
}

__device__ __forceinline__ void store_accfrag(float* __restrict__ dst, int lane, int w,
                                              f32x4 a, long rs) {
    int n = (w << 4) + (lane & 15);
#pragma unroll
    for (int r = 0; r < 4; r++) {
        int b = (((lane >> 4) & 3) << 2) + r;
        dst[(long)b * rs + n] = a[r];
    }
}

// ---------------- prep: fused matrices (fp32, row-major) ----------------
// A2m=A*A, ABm=A*B, Gm=C*A, Hm=C*B+D
__global__ __launch_bounds__(128) void k_prep1(const float* __restrict__ A,
                                               const float* __restrict__ B,
                                               const float* __restrict__ C,
                                               const float* __restrict__ D,
                                               float* __restrict__ A2m, float* __restrict__ ABm,
                                               float* __restrict__ Gm,  float* __restrict__ Hm) {
    int sel = blockIdx.x >> 7, r = blockIdx.x & 127, j = threadIdx.x;
    const float* L = (sel < 2) ? A : C;
    const float* R = (sel == 0 || sel == 2) ? A : B;
    float s = 0.f;
#pragma unroll 8
    for (int m = 0; m < 128; m++) s = fmaf(L[r * 128 + m], R[m * 128 + j], s);
    if      (sel == 0) A2m[r * 128 + j] = s;
    else if (sel == 1) ABm[r * 128 + j] = s;
    else if (sel == 2) Gm[r * 128 + j]  = s;
    else               Hm[r * 128 + j]  = s + D[r * 128 + j];
}

// G2m=Gm*A (=CA^2), H2m=Gm*B (=CAB)
__global__ __launch_bounds__(128) void k_prep2(const float* __restrict__ A,
                                               const float* __restrict__ B,
                                               const float* __restrict__ Gm,
                                               float* __restrict__ G2m, float* __restrict__ H2m) {
    int sel = blockIdx.x >> 7, r = blockIdx.x & 127, j = threadIdx.x;
    const float* R = sel ? B : A;
    float s = 0.f;
#pragma unroll 8
    for (int m = 0; m < 128; m++) s = fmaf(Gm[r * 128 + m], R[m * 128 + j], s);
    (sel ? H2m : G2m)[r * 128 + j] = s;
}

// ---------------- k_chunk: local chunk scans (2-step) + P = (A^T)^CL ----------------
__global__ __launch_bounds__(512, 2) void k_chunk(const float* __restrict__ u,
                                                  const float* __restrict__ A2m,
                                                  const float* __restrict__ ABm,
                                                  const float* __restrict__ Bm,
                                                  float* __restrict__ E,
                                                  float* __restrict__ P) {
    __shared__ __align__(16) bf16t Xh[2][BS * DD], Xl[2][BS * DD];
    __shared__ __align__(16) bf16t Uh[2][2][BS * DD], Ul[2][2][BS * DD];
    int tid = threadIdx.x, lane = tid & 63, w = tid >> 6;
    bool ident = blockIdx.x >= NC;
    int g2 = blockIdx.x - NC;

    Frag fA2, fAB, fB;
    load_frag_T(A2m, lane, w, fA2);
    if (!ident) { load_frag_T(ABm, lane, w, fAB); load_frag_T(Bm, lane, w, fB); }

    for (int i = tid; i < BS * DD; i += 512) {
        int b = i >> 7, j = swz(b, i & 127);
        float v = (ident && j == g2 * 16 + b) ? 1.f : 0.f;
        Xh[0][i] = (bf16t)v;
        Xl[0][i] = (bf16t)0.f;
    }
    int c = blockIdx.x;
    const float* ubase = u + (long)c * CL * DD;
    int b_ = tid >> 5, j0_ = (tid & 31) << 2;
    if (!ident) {
        stage_rows(ubase,      (long)SEQ * DD, Uh[0][0], Ul[0][0], tid);
        stage_rows(ubase + DD, (long)SEQ * DD, Uh[0][1], Ul[0][1], tid);
    }
    __syncthreads();

    int p = 0;
    f32x4 acc = {0.f, 0.f, 0.f, 0.f};
    for (int j = 0; j < PH; j++) {
        int jb = j & 1;
        float4 un1 = {0,0,0,0}, un2 = {0,0,0,0};
        if (!ident && j + 1 < PH) {
            const float* nb = ubase + (long)b_ * SEQ * DD + (2 * j + 2) * DD + j0_;
            un1 = *(const float4*)(nb);
            un2 = *(const float4*)(nb + DD);
        }
        f32x4 ax = {0,0,0,0}, ax2 = {0,0,0,0}, ax3 = {0,0,0,0};
#pragma unroll
        for (int q = 0; q < 4; q++) {
            bf16x8 xh = afrag(Xh[p], lane, q), xl = afrag(Xl[p], lane, q);
            ax  = MFMA(xh, fA2.h[q], ax);
            ax2 = MFMA(xl, fA2.h[q], ax2);
            ax3 = MFMA(xh, fA2.l[q], ax3);
            if (!ident) {
                bf16x8 u1h = afrag(Uh[jb][0], lane, q), u1l = afrag(Ul[jb][0], lane, q);
                bf16x8 u2h = afrag(Uh[jb][1], lane, q), u2l = afrag(Ul[jb][1], lane, q);
                ax  = MFMA(u1h, fAB.h[q], ax);
                ax2 = MFMA(u1l, fAB.h[q], ax2);
                ax3 = MFMA(u1h, fAB.l[q], ax3);
                ax  = MFMA(u2h, fB.h[q], ax);
                ax2 = MFMA(u2l, fB.h[q], ax2);
                ax3 = MFMA(u2h, fB.l[q], ax3);
            }
        }
        acc = ax + ax2 + ax3;
        if (j + 1 < PH) {
            put_state(Xh[p ^ 1], Xl[p ^ 1], lane, w, acc);
            if (!ident) {
                write_u(Uh[jb ^ 1][0], Ul[jb ^ 1][0], b_, j0_, un1);
                write_u(Uh[jb ^ 1][1], Ul[jb ^ 1][1], b_, j0_, un2);
            }
            __syncthreads();
            p ^= 1;
        }
    }
    if (!ident) store_accfrag(E + (long)c * BS * DD, lane, w, acc, DD);
    else        store_accfrag(P + (long)g2 * 16 * DD, lane, w, acc, DD);
}

// ---------------- k_group: E2[g] over 16 chunks + Pg = P^16 ----------------
__global__ __launch_bounds__(512) void k_group(const float* __restrict__ E,
                                               const float* __restrict__ P,
                                               float* __restrict__ E2,
                                               float* __restrict__ Pg) {
    __shared__ __align__(16) bf16t Xh[2][BS * DD], Xl[2][BS * DD];
    int tid = threadIdx.x, lane = tid & 63, w = tid >> 6;
    bool ident = blockIdx.x >= NG;
    int g2 = blockIdx.x - NG;
    Frag fP;
    load_frag_N(P, lane, w, fP);
    for (int i = tid; i < BS * DD; i += 512) {
        int b = i >> 7, j = swz(b, i & 127);
        float v = (ident && j == g2 * 16 + b) ? 1.f : 0.f;
        Xh[0][i] = (bf16t)v;
        Xl[0][i] = (bf16t)0.f;
    }
    __syncthreads();
    int p = 0, g = blockIdx.x;
    f32x4 acc = {0.f, 0.f, 0.f, 0.f};
    for (int r = 0; r < GRP; r++) {
        f32x4 a1 = {0.f,0.f,0.f,0.f}, a2 = {0.f,0.f,0.f,0.f};
        if (!ident) a1 = load_accfrag(E + (long)(g * GRP + r) * BS * DD, lane, w);
#pragma unroll
        for (int q = 0; q < 4; q++) {
            bf16x8 xh = afrag(Xh[p], lane, q), xl = afrag(Xl[p], lane, q);
            a1 = MFMA(xh, fP.h[q], a1);
            a2 = MFMA(xl, fP.h[q], a2);
            a1 = MFMA(xh, fP.l[q], a1);
        }
        acc = a1 + a2;
        if (r + 1 < GRP) {
            put_state(Xh[p ^ 1], Xl[p ^ 1], lane, w, acc);
            __syncthreads();
            p ^= 1;
        }
    }
    if (!ident) store_accfrag(E2 + (long)g * BS * DD, lane, w, acc, DD);
    else        store_accfrag(Pg + (long)g2 * 16 * DD, lane, w, acc, DD);
}

// ---------------- k_top: 1 wg, group entry states S2[g] ----------------
__global__ __launch_bounds__(512) void k_top(const float* __restrict__ E2,
                                             const float* __restrict__ Pg,
                                             float* __restrict__ S2) {
    __shared__ __align__(16) bf16t Xh[2][BS * DD], Xl[2][BS * DD];
    int tid = threadIdx.x, lane = tid & 63, w = tid >> 6;
    Frag fP;
    load_frag_N(Pg, lane, w, fP);
    for (int i = tid; i < BS * DD; i += 512) {
        Xh[0][i] = (bf16t)0.f;
        Xl[0][i] = (bf16t)0.f;
    }
    __syncthreads();
    int p = 0;
    f32x4 T = {0.f, 0.f, 0.f, 0.f};
    for (int g = 0; g < NG; g++) {
        store_accfrag(S2 + (long)g * BS * DD, lane, w, T, DD);
        f32x4 a1 = load_accfrag(E2 + (long)g * BS * DD, lane, w), a2 = {0.f,0.f,0.f,0.f};
#pragma unroll
        for (int q = 0; q < 4; q++) {
            bf16x8 xh = afrag(Xh[p], lane, q), xl = afrag(Xl[p], lane, q);
            a1 = MFMA(xh, fP.h[q], a1);
            a2 = MFMA(xl, fP.h[q], a2);
            a1 = MFMA(xh, fP.l[q], a1);
        }
        T = a1 + a2;
        if (g + 1 < NG) {
            put_state(Xh[p ^ 1], Xl[p ^ 1], lane, w, T);
            __syncthreads();
            p ^= 1;
        }
    }
}

// ---------------- k_fix: chunk entry states S[c] ----------------
__global__ __launch_bounds__(512) void k_fix(const float* __restrict__ E,
                                             const float* __restrict__ P,
                                             const float* __restrict__ S2,
                                             float* __restrict__ S) {
    __shared__ __align__(16) bf16t Xh[2][BS * DD], Xl[2][BS * DD];
    int tid = threadIdx.x, lane = tid & 63, w = tid >> 6;
    int g = blockIdx.x;
    Frag fP;
    load_frag_N(P, lane, w, fP);
    stage_rows(S2 + (long)g * BS * DD, DD, Xh[0], Xl[0], tid);
    f32x4 T = load_accfrag(S2 + (long)g * BS * DD, lane, w);
    __syncthreads();
    int p = 0;
    for (int r = 0; r < GRP; r++) {
        int c = g * GRP + r;
        store_accfrag(S + (long)c * BS * DD, lane, w, T, DD);
        if (r + 1 == GRP) break;
        f32x4 a1 = load_accfrag(E + (long)c * BS * DD, lane, w), a2 = {0.f,0.f,0.f,0.f};
#pragma unroll
        for (int q = 0; q < 4; q++) {
            bf16x8 xh = afrag(Xh[p], lane, q), xl = afrag(Xl[p], lane, q);
            a1 = MFMA(xh, fP.h[q], a1);
            a2 = MFMA(xl, fP.h[q], a2);
            a1 = MFMA(xh, fP.l[q], a1);
        }
        T = a1 + a2;
        put_state(Xh[p ^ 1], Xl[p ^ 1], lane, w, T);
        __syncthreads();
        p ^= 1;
    }
}

// ---------------- k_main: final 2-step scan, fused y ----------------
__global__ __launch_bounds__(512, 2) void k_main(const float* __restrict__ u,
                                                 const float* __restrict__ A2m,
                                                 const float* __restrict__ ABm,
                                                 const float* __restrict__ Bm,
                                                 const float* __restrict__ Gm,
                                                 const float* __restrict__ Hm,
                                                 const float* __restrict__ G2m,
                                                 const float* __restrict__ H2m,
                                                 const float* __restrict__ S,
                                                 float* __restrict__ out) {
    __shared__ __align__(16) bf16t Xh[2][BS * DD], Xl[2][BS * DD];
    __shared__ __align__(16) bf16t Uh[2][2][BS * DD], Ul[2][2][BS * DD];
    int tid = threadIdx.x, lane = tid & 63, w = tid >> 6;
    Frag fA2, fAB, fB;
    FragH fG, fH, fG2, fH2;
    load_frag_T(A2m, lane, w, fA2);
    load_frag_T(ABm, lane, w, fAB);
    load_frag_T(Bm,  lane, w, fB);
    load_frag_T_h(Gm,  lane, w, fG);
    load_frag_T_h(Hm,  lane, w, fH);
    load_frag_T_h(G2m, lane, w, fG2);
    load_frag_T_h(H2m, lane, w, fH2);
    int c = blockIdx.x;
    const float* ubase = u + (long)c * CL * DD;
    int b_ = tid >> 5, j0_ = (tid & 31) << 2;
    stage_rows(S + (long)c * BS * DD, DD, Xh[0], Xl[0], tid);
    stage_rows(ubase,      (long)SEQ * DD, Uh[0][0], Ul[0][0], tid);
    stage_rows(ubase + DD, (long)SEQ * DD, Uh[0][1], Ul[0][1], tid);
    __syncthreads();
    int p = 0;
    for (int j = 0; j < PH; j++) {
        int jb = j & 1;
        float4 un1 = {0,0,0,0}, un2 = {0,0,0,0};
        if (j + 1 < PH) {
            const float* nb = ubase + (long)b_ * SEQ * DD + (2 * j + 2) * DD + j0_;
            un1 = *(const float4*)(nb);
            un2 = *(const float4*)(nb + DD);
        }
        f32x4 ax = {0,0,0,0}, ax2 = {0,0,0,0}, ax3 = {0,0,0,0};
        f32x4 ay1 = {0,0,0,0}, ay1b = {0,0,0,0};
        f32x4 ay2 = {0,0,0,0}, ay2b = {0,0,0,0}, ay2c = {0,0,0,0};
#pragma unroll
        for (int q = 0; q < 4; q++) {
            bf16x8 xh  = afrag(Xh[p], lane, q),      xl  = afrag(Xl[p], lane, q);
            bf16x8 u1h = afrag(Uh[jb][0], lane, q),  u1l = afrag(Ul[jb][0], lane, q);
            bf16x8 u2h = afrag(Uh[jb][1], lane, q),  u2l = afrag(Ul[jb][1], lane, q);
            ax  = MFMA(xh,  fA2.h[q], ax);
            ax2 = MFMA(xl,  fA2.h[q], ax2);
            ax3 = MFMA(xh,  fA2.l[q], ax3);
            ax  = MFMA(u1h, fAB.h[q], ax);
            ax2 = MFMA(u1l, fAB.h[q], ax2);
            ax3 = MFMA(u1h, fAB.l[q], ax3);
            ax  = MFMA(u2h, fB.h[q],  ax);
            ax2 = MFMA(u2l, fB.h[q],  ax2);
            ax3 = MFMA(u2h, fB.l[q],  ax3);
            ay1  = MFMA(xh,  fG.h[q],  ay1);
            ay1b = MFMA(u1h, fH.h[q],  ay1b);
            ay2  = MFMA(xh,  fG2.h[q], ay2);
            ay2b = MFMA(u1h, fH2.h[q], ay2b);
            ay2c = MFMA(u2h, fH.h[q],  ay2c);
        }
        f32x4 xnew = ax + ax2 + ax3;
        if (j + 1 < PH) {
            put_state(Xh[p ^ 1], Xl[p ^ 1], lane, w, xnew);
            write_u(Uh[jb ^ 1][0], Ul[jb ^ 1][0], b_, j0_, un1);
            write_u(Uh[jb ^ 1][1], Ul[jb ^ 1][1], b_, j0_, un2);
        }
        f32x4 y1 = ay1 + ay1b;
        f32x4 y2 = ay2 + ay2b + ay2c;
        long t0 = (long)c * CL + 2 * j;
        store_accfrag(out + t0 * DD,       lane, w, y1, (long)SEQ * DD);
        store_accfrag(out + (t0 + 1) * DD, lane, w, y2, (long)SEQ * DD);
        if (j + 1 < PH) {
            __syncthreads();
            p ^= 1;
        }
    }
}

extern "C" void kernel_launch(void* const* d_in, const int* in_sizes, int n_in,
                              void* d_out, int out_size, void* d_ws, size_t ws_size,
                              hipStream_t stream) {
    (void)in_sizes; (void)n_in; (void)out_size; (void)ws_size;
    const float* u = (const float*)d_in[0];
    const float* A = (const float*)d_in[1];
    const float* B = (const float*)d_in[2];
    const float* C = (const float*)d_in[3];
    const float* D = (const float*)d_in[4];
    float* out = (float*)d_out;
    float* ws  = (float*)d_ws;
    // ws layout (floats):
    float* P   = ws;              // 16384
    float* Pg  = P   + 16384;     // 16384
    float* A2m = Pg  + 16384;     // 16384
    float* ABm = A2m + 16384;     // 16384
    float* Gm  = ABm + 16384;     // 16384
    float* Hm  = Gm  + 16384;     // 16384
    float* G2m = Hm  + 16384;     // 16384
    float* H2m = G2m + 16384;     // 16384
    float* E   = H2m + 16384;     // 524288
    float* E2  = E   + 524288;    // 32768
    float* S2  = E2  + 32768;     // 32768
    float* S   = S2  + 32768;     // 524288  -> total ~4.75 MiB
    dim3 blk(512);
    k_prep1<<<512, 128, 0, stream>>>(A, B, C, D, A2m, ABm, Gm, Hm);
    k_prep2<<<256, 128, 0, stream>>>(A, B, Gm, G2m, H2m);
    k_chunk<<<NC + 8, blk, 0, stream>>>(u, A2m, ABm, B, E, P);
    k_group<<<NG + 8, blk, 0, stream>>>(E, P, E2, Pg);
    k_top  <<<1,      blk, 0, stream>>>(E2, Pg, S2);
    k_fix  <<<NG,     blk, 0, stream>>>(E, P, S2, S);
    k_main <<<NC,     blk, 0, stream>>>(u, A2m, ABm, B, Gm, Hm, G2m, H2m, S, out);
}